// Round 7
// baseline (1209.936 us; speedup 1.0000x reference)
//
#include <hip/hip_runtime.h>
#include <hip/hip_bf16.h>
#include <stdint.h>

// TreeLSTM on MI355X (gfx950) — fully fused subtree kernel, v4.
// Each block owns 8 level-3 roots => 64 leaves. All h/c state lives in LDS.
// v4: (1) logits stashed in LDS, ONE scattered-store burst at kernel end
//     (no mid-kernel vmcnt(0)+barrier drains of cross-XCD stores);
//     (2) 3 blocks/CU: leaf level in two 32-row halves + in-place c-arena
//     ([p][68] padded, slot s of level l at index s<<l; same-thread
//     read-then-write makes aliasing safe) => LDS 53.8KB, launch_bounds(512,6);
//     (3) exp/rcp-based tanh/sigmoid (no tanhf libcalls).

#define THREADS 512

typedef __attribute__((ext_vector_type(8))) short short8;
typedef __attribute__((ext_vector_type(4))) float f32x4;
typedef f32x4 __attribute__((aligned(4))) f32x4u;   // 4B-aligned vec store

__device__ __forceinline__ unsigned short f2bf(float x) {
    unsigned u = __float_as_uint(x);
    u += 0x7fffu + ((u >> 16) & 1u);   // round-to-nearest-even
    return (unsigned short)(u >> 16);
}
__device__ __forceinline__ float bf2f(unsigned short b) {
    return __uint_as_float(((unsigned)b) << 16);
}
__device__ __forceinline__ float rcp_fast(float x) { return __builtin_amdgcn_rcpf(x); }
__device__ __forceinline__ float sigm(float x) { return rcp_fast(1.f + __expf(-x)); }
__device__ __forceinline__ float tanh_fast(float x) {
    float e = __expf(2.f * x);
    return (e - 1.f) * rcp_fast(e + 1.f);
}

// ---------------------------------------------------------------------------
// Pack W_iou (384x256) -> Wl ; [U_iou (384x256); U_f (256x256)] -> Wc (640x256)
__global__ __launch_bounds__(256)
void prep_kernel(const float* __restrict__ W_iou,
                 const float* __restrict__ U_iou,
                 const float* __restrict__ U_f,
                 unsigned short* __restrict__ Wl,
                 unsigned short* __restrict__ Wc)
{
    const int i = blockIdx.x * 256 + threadIdx.x;   // grid covers 98304
    if (i < 98304) {
        Wl[i] = f2bf(W_iou[i]);
        Wc[i] = f2bf(U_iou[i]);
    }
    if (i < 65536) {
        Wc[98304 + i] = f2bf(U_f[i]);
    }
}

// ---------------------------------------------------------------------------
// One level's GEMM + LSTM epilogue.
// B-tile rows (512B, XOR-16B-chunk swizzled): row j = [h_prev[2j]|h_prev[2j+1]]
// (leaves: row i = emb[tok[i]]). Swapped MFMA: D[n][node]; wave w owns the
// p-slice [16w,16w+16); col groups n = p + j*128 keep i,o,u,f0,f1 in one lane.
// c-arena: one [p][68]-padded ushort buffer; level-l slot s at index s<<l.
// CW = 1<<level. Children of node ml sit at CW*ml and CW*ml + CW/2; own c is
// written at CW*ml (aliases first child; same thread reads both first).
template<int NCOL, int G, int CW, bool WC>
__device__ __forceinline__ void level_step(
    const unsigned short* __restrict__ Wg,     // [NCOL*128][256] bf16, global
    const unsigned char* Blds,                 // B-tile base in LDS
    unsigned char* h_out,                      // LDS, B-tile format for next level
    unsigned short* cAr,                       // LDS c-arena, stride 68 per p
    const float* __restrict__ b_iou, const float* __restrict__ b_f,
    int w, int lrow, int lk, int slotBase, int mrows)
{
    const int q0 = w * 16;
    const unsigned char* wbase = reinterpret_cast<const unsigned char*>(Wg)
                               + (q0 + lrow) * 512 + lk * 16;

    f32x4 acc[NCOL][G];
    #pragma unroll
    for (int j = 0; j < NCOL; ++j)
        #pragma unroll
        for (int g = 0; g < G; ++g)
            acc[j][g] = (f32x4){0.f, 0.f, 0.f, 0.f};

    short8 a0[NCOL], a1[NCOL];
    #pragma unroll
    for (int j = 0; j < NCOL; ++j)
        a0[j] = *reinterpret_cast<const short8*>(wbase + j * 65536);

    #pragma unroll
    for (int ks = 0; ks < 8; ++ks) {
        if (ks < 7) {                       // prefetch ks+1 into the other buf
            #pragma unroll
            for (int j = 0; j < NCOL; ++j) {
                short8 v = *reinterpret_cast<const short8*>(
                    wbase + j * 65536 + (ks + 1) * 64);
                if (ks & 1) a0[j] = v; else a1[j] = v;
            }
        }
        #pragma unroll
        for (int g = 0; g < G; ++g) {
            const int row = g * 16 + lrow;          // B-tile row
            const int chunk = (ks * 4 + lk) ^ (row & 7);
            short8 bN = *reinterpret_cast<const short8*>(
                Blds + row * 512 + (chunk << 4));
            #pragma unroll
            for (int j = 0; j < NCOL; ++j) {
                short8 a = (ks & 1) ? a1[j] : a0[j];   // static after unroll
                acc[j][g] = __builtin_amdgcn_mfma_f32_16x16x32_bf16(
                    a, bN, acc[j][g], 0, 0, 0);
            }
        }
    }

    #pragma unroll
    for (int g = 0; g < G; ++g) {
        const int mlB = g * 16 + lrow;              // B-tile row index
        if (mlB < mrows) {
            const int ml = slotBase + mlB;          // output slot this level
            #pragma unroll
            for (int r = 0; r < 4; ++r) {
                const int p = q0 + lk * 4 + r;
                float iv = acc[0][g][r] + b_iou[p];
                float ov = acc[1][g][r] + b_iou[128 + p];
                float uv = acc[2][g][r] + b_iou[256 + p];
                float csum = 0.f;
                if (NCOL == 5) {
                    float f0 = acc[3][g][r] + b_f[p];
                    float f1 = acc[4][g][r] + b_f[128 + p];
                    const int cb = p * 68 + CW * mlB;
                    csum = sigm(f0) * bf2f(cAr[cb])
                         + sigm(f1) * bf2f(cAr[cb + CW / 2]);
                }
                float cv = sigm(iv) * tanh_fast(uv) + csum;
                float hv = sigm(ov) * tanh_fast(cv);
                if (WC) cAr[p * 68 + CW * ml] = f2bf(cv);
                const int jr = ml >> 1;
                const int q = (ml & 1) * 16 + (p >> 3);
                *reinterpret_cast<unsigned short*>(
                    h_out + jr * 512 + ((q ^ (jr & 7)) << 4) + (p & 7) * 2)
                    = f2bf(hv);
            }
        }
    }
}

// logits for M local nodes from swizzled LDS h; 4 lanes per node.
// Dots (no bias) go to the LDS stash; global store happens once at kernel end.
__device__ __forceinline__ void logits_stash(
    const unsigned char* h_lds, int M, int stBase,
    const float* __restrict__ W_lin, float* sL, int t)
{
    const int s = t >> 2, sub = t & 3;
    if (s >= M) return;
    float hv[32];
    const int j = s >> 1;
    #pragma unroll
    for (int qq = 0; qq < 4; ++qq) {
        const int q = (s & 1) * 16 + sub * 4 + qq;
        short8 v = *reinterpret_cast<const short8*>(
            h_lds + j * 512 + ((q ^ (j & 7)) << 4));
        #pragma unroll
        for (int e = 0; e < 8; ++e) hv[qq * 8 + e] = bf2f((unsigned short)v[e]);
    }
    float dots[5];
    #pragma unroll
    for (int cl = 0; cl < 5; ++cl) {
        const float* wr = W_lin + cl * 128 + sub * 32;
        float d = 0.f;
        #pragma unroll
        for (int k = 0; k < 32; ++k) d += hv[k] * wr[k];
        d += __shfl_xor(d, 1);
        d += __shfl_xor(d, 2);
        dots[cl] = d;
    }
    if (sub == 0) {
        #pragma unroll
        for (int cl = 0; cl < 5; ++cl)
            sL[(stBase + s) * 5 + cl] = dots[cl];
    }
}

// ---------------------------------------------------------------------------
__global__ __launch_bounds__(THREADS, 6)   // 6 waves/EU => 3 blocks/CU; VGPR<=85
void tree_kernel(const int*  __restrict__ leaf_x,
                 const int2* __restrict__ cpairs,   // l1:[0,131072) l2:+131072 l3:+196608
                 const float* __restrict__ emb,
                 const unsigned short* __restrict__ Wl,
                 const unsigned short* __restrict__ Wc,
                 const float* __restrict__ b_iou,
                 const float* __restrict__ b_f,
                 const float* __restrict__ W_lin,
                 const float* __restrict__ b_lin,
                 float* __restrict__ out)
{
    // Arena (52576 B), region-overlaid (lifetimes commented):
    //   X0  [0,16384)      leaf half B-tile (32 rows x 512B); dead after leaf
    //   h0  [16384,32768)  64 leaf slots (32 rows); dead after L1 GEMM
    //   cAr [32768,50176)  [p=128][68] ushort in-place c-arena, whole kernel
    //   sL  [50176,52576)  120x5 f32 logits stash, whole kernel
    //   h1  [0,8192)       over X0 after leaf barrier; dead after L2 GEMM
    //   h2  [16384,20480)  over h0 after L1 barrier (L3 GEMM also reads
    //                      stale rows 8..15 at [20480,24576); masked)
    //   h3  [0,2048)       over h1 after L2 barrier
    __shared__ __align__(16) unsigned char arena[52576];
    __shared__ int ids0[64], ids1[32], ids2[16], tok[64], sg[120];

    const int t    = threadIdx.x;
    const int lane = t & 63;
    const int w    = t >> 6;       // wave = p-slice, 8 waves
    const int lrow = lane & 15;
    const int lk   = lane >> 4;
    const int blk3 = blockIdx.x * 8;   // 8 level-3 roots per block

    // ---- id chase: local slot s's children are local slots 2s,2s+1 ----
    if (t < 8)  { int2 p = cpairs[196608 + blk3 + t]; ids2[2*t] = p.x; ids2[2*t+1] = p.y; }
    __syncthreads();
    if (t < 16) { int2 p = cpairs[131072 + ids2[t]];  ids1[2*t] = p.x; ids1[2*t+1] = p.y; }
    __syncthreads();
    if (t < 32) { int2 p = cpairs[ids1[t]];           ids0[2*t] = p.x; ids0[2*t+1] = p.y; }
    __syncthreads();
    if      (t < 64)  { tok[t] = leaf_x[ids0[t]]; sg[t] = ids0[t]; }
    else if (t < 96)  { sg[t] = 262144 + ids1[t - 64]; }
    else if (t < 112) { sg[t] = 393216 + ids2[t - 96]; }
    else if (t < 120) { sg[t] = 458752 + blk3 + (t - 112); }
    __syncthreads();

    unsigned char*  X0  = arena;
    unsigned char*  h0  = arena + 16384;
    unsigned short* cAr = (unsigned short*)(arena + 32768);
    float*          sL  = (float*)(arena + 50176);
    unsigned char*  h1  = arena;
    unsigned char*  h2  = arena + 16384;
    unsigned char*  h3  = arena;

    // ---- leaves: 64 nodes in two 32-row halves ----
    #pragma unroll 1
    for (int half = 0; half < 2; ++half) {
        {
            const int c  = t & 31;      // 16B chunk
            const int r0 = t >> 5;      // [0,16)
            #pragma unroll
            for (int rr = 0; rr < 2; ++rr) {
                const int r  = r0 + rr * 16;           // [0,32)
                const int gi = tok[half * 32 + r];
                const float4* src = reinterpret_cast<const float4*>(
                    emb + (size_t)gi * 256 + c * 8);
                float4 a = src[0], b = src[1];
                short8 v;
                v[0]=(short)f2bf(a.x); v[1]=(short)f2bf(a.y);
                v[2]=(short)f2bf(a.z); v[3]=(short)f2bf(a.w);
                v[4]=(short)f2bf(b.x); v[5]=(short)f2bf(b.y);
                v[6]=(short)f2bf(b.z); v[7]=(short)f2bf(b.w);
                *reinterpret_cast<short8*>(X0 + r * 512 + ((c ^ (r & 7)) << 4)) = v;
            }
        }
        __syncthreads();
        level_step<3, 2, 1, true>(Wl, X0, h0, cAr, b_iou, b_f,
                                  w, lrow, lk, half * 32, 32);
        __syncthreads();
    }

    // ---- level 1: 32 nodes ----
    logits_stash(h0, 64, 0, W_lin, sL, t);
    level_step<5, 2, 2, true>(Wc, h0, h1, cAr, b_iou, b_f,
                              w, lrow, lk, 0, 32);
    __syncthreads();

    // ---- level 2: 16 nodes ----
    logits_stash(h1, 32, 64, W_lin, sL, t);
    level_step<5, 1, 4, true>(Wc, h1, h2, cAr, b_iou, b_f,
                              w, lrow, lk, 0, 16);
    __syncthreads();

    // ---- level 3: 8 nodes (rows 8..15 of the 16-row m-group are stale; masked)
    logits_stash(h2, 16, 96, W_lin, sL, t);
    level_step<5, 1, 8, false>(Wc, h2, h3, cAr, b_iou, b_f,
                               w, lrow, lk, 0, 8);
    __syncthreads();

    logits_stash(h3, 8, 112, W_lin, sL, t);
    __syncthreads();

    // ---- single scattered-store burst; no barrier after (drains at kernel end)
    if (t < 120) {
        const float* sp = sL + t * 5;
        float* op = out + (size_t)sg[t] * 5;
        f32x4 v4 = { sp[0] + b_lin[0], sp[1] + b_lin[1],
                     sp[2] + b_lin[2], sp[3] + b_lin[3] };
        *reinterpret_cast<f32x4u*>(op) = v4;
        op[4] = sp[4] + b_lin[4];
    }
}

// ---------------------------------------------------------------------------
extern "C" void kernel_launch(void* const* d_in, const int* in_sizes, int n_in,
                              void* d_out, int out_size, void* d_ws, size_t ws_size,
                              hipStream_t stream)
{
    const int*   leaf_x = (const int*)d_in[0];
    const int*   child  = (const int*)d_in[1];
    const float* emb    = (const float*)d_in[2];
    const float* W_iou  = (const float*)d_in[3];
    const float* U_iou  = (const float*)d_in[4];
    const float* b_iou  = (const float*)d_in[5];
    const float* U_f    = (const float*)d_in[6];
    const float* b_f    = (const float*)d_in[7];
    const float* W_lin  = (const float*)d_in[8];
    const float* b_lin  = (const float*)d_in[9];
    float* out = (float*)d_out;

    char* ws = (char*)d_ws;
    unsigned short* Wl = (unsigned short*)ws;                 // 192 KiB
    unsigned short* Wc = (unsigned short*)(ws + 196608);      // 320 KiB

    prep_kernel<<<384, 256, 0, stream>>>(W_iou, U_iou, U_f, Wl, Wc);

    tree_kernel<<<4096, THREADS, 0, stream>>>(
        leaf_x, (const int2*)child, emb, Wl, Wc,
        b_iou, b_f, W_lin, b_lin, out);
}

// Round 8
// 1181.148 us; speedup vs baseline: 1.0244x; 1.0244x over previous
//
#include <hip/hip_runtime.h>
#include <hip/hip_bf16.h>
#include <stdint.h>

// TreeLSTM on MI355X (gfx950) — fully fused subtree kernel, v5.
// Each block owns 8 level-3 roots => 64 leaves. All h/c state lives in LDS.
// v5 = v4 minus the explicit W double-buffer (it caused an accumulator spill
// under the launch_bounds(512,6) VGPR cap: VGPR=40 + 3.4GB scratch traffic).
// Simple per-ks W loads compile to ~64 VGPR -> fits under the 85 cap ->
// 3 blocks/CU (24 waves) for latency hiding. Keeps: LDS logits stash with ONE
// scattered-store burst at kernel end; in-place [p][68] c-arena; exp/rcp
// tanh/sigmoid; idempotent weight packing in d_ws (replay/poison-proof).

#define THREADS 512

typedef __attribute__((ext_vector_type(8))) short short8;
typedef __attribute__((ext_vector_type(4))) float f32x4;
typedef f32x4 __attribute__((aligned(4))) f32x4u;   // 4B-aligned vec store

__device__ __forceinline__ unsigned short f2bf(float x) {
    unsigned u = __float_as_uint(x);
    u += 0x7fffu + ((u >> 16) & 1u);   // round-to-nearest-even
    return (unsigned short)(u >> 16);
}
__device__ __forceinline__ float bf2f(unsigned short b) {
    return __uint_as_float(((unsigned)b) << 16);
}
__device__ __forceinline__ float rcp_fast(float x) { return __builtin_amdgcn_rcpf(x); }
__device__ __forceinline__ float sigm(float x) { return rcp_fast(1.f + __expf(-x)); }
__device__ __forceinline__ float tanh_fast(float x) {
    float e = __expf(2.f * x);
    return (e - 1.f) * rcp_fast(e + 1.f);
}

// ---------------------------------------------------------------------------
// Pack W_iou (384x256) -> Wl ; [U_iou (384x256); U_f (256x256)] -> Wc (640x256)
__global__ __launch_bounds__(256)
void prep_kernel(const float* __restrict__ W_iou,
                 const float* __restrict__ U_iou,
                 const float* __restrict__ U_f,
                 unsigned short* __restrict__ Wl,
                 unsigned short* __restrict__ Wc)
{
    const int i = blockIdx.x * 256 + threadIdx.x;   // grid covers 98304
    if (i < 98304) {
        Wl[i] = f2bf(W_iou[i]);
        Wc[i] = f2bf(U_iou[i]);
    }
    if (i < 65536) {
        Wc[98304 + i] = f2bf(U_f[i]);
    }
}

// ---------------------------------------------------------------------------
// One level's GEMM + LSTM epilogue.
// B-tile rows (512B, XOR-16B-chunk swizzled): row j = [h_prev[2j]|h_prev[2j+1]]
// (leaves: row i = emb[tok[i]]). Swapped MFMA: D[n][node]; wave w owns the
// p-slice [16w,16w+16); col groups n = p + j*128 keep i,o,u,f0,f1 in one lane.
// c-arena: one [p][68]-padded ushort buffer; level-l slot s at index s<<l.
// CW = 1<<level. Children of node ml sit at CW*ml and CW*ml + CW/2; own c is
// written at CW*ml (aliases first child; same thread reads both first).
template<int NCOL, int G, int CW, bool WC>
__device__ __forceinline__ void level_step(
    const unsigned short* __restrict__ Wg,     // [NCOL*128][256] bf16, global
    const unsigned char* Blds,                 // B-tile base in LDS
    unsigned char* h_out,                      // LDS, B-tile format for next level
    unsigned short* cAr,                       // LDS c-arena, stride 68 per p
    const float* __restrict__ b_iou, const float* __restrict__ b_f,
    int w, int lrow, int lk, int slotBase, int mrows)
{
    const int q0 = w * 16;
    const unsigned char* wbase = reinterpret_cast<const unsigned char*>(Wg)
                               + (q0 + lrow) * 512 + lk * 16;

    f32x4 acc[NCOL][G];
    #pragma unroll
    for (int j = 0; j < NCOL; ++j)
        #pragma unroll
        for (int g = 0; g < G; ++g)
            acc[j][g] = (f32x4){0.f, 0.f, 0.f, 0.f};

    #pragma unroll
    for (int ks = 0; ks < 8; ++ks) {
        short8 aW[NCOL];
        #pragma unroll
        for (int j = 0; j < NCOL; ++j)
            aW[j] = *reinterpret_cast<const short8*>(
                wbase + j * 65536 + ks * 64);
        #pragma unroll
        for (int g = 0; g < G; ++g) {
            const int row = g * 16 + lrow;          // B-tile row
            const int chunk = (ks * 4 + lk) ^ (row & 7);
            short8 bN = *reinterpret_cast<const short8*>(
                Blds + row * 512 + (chunk << 4));
            #pragma unroll
            for (int j = 0; j < NCOL; ++j)
                acc[j][g] = __builtin_amdgcn_mfma_f32_16x16x32_bf16(
                    aW[j], bN, acc[j][g], 0, 0, 0);
        }
    }

    #pragma unroll
    for (int g = 0; g < G; ++g) {
        const int mlB = g * 16 + lrow;              // B-tile row index
        if (mlB < mrows) {
            const int ml = slotBase + mlB;          // output slot this level
            #pragma unroll
            for (int r = 0; r < 4; ++r) {
                const int p = q0 + lk * 4 + r;
                float iv = acc[0][g][r] + b_iou[p];
                float ov = acc[1][g][r] + b_iou[128 + p];
                float uv = acc[2][g][r] + b_iou[256 + p];
                float csum = 0.f;
                if (NCOL == 5) {
                    float f0 = acc[3][g][r] + b_f[p];
                    float f1 = acc[4][g][r] + b_f[128 + p];
                    const int cb = p * 68 + CW * mlB;
                    csum = sigm(f0) * bf2f(cAr[cb])
                         + sigm(f1) * bf2f(cAr[cb + CW / 2]);
                }
                float cv = sigm(iv) * tanh_fast(uv) + csum;
                float hv = sigm(ov) * tanh_fast(cv);
                if (WC) cAr[p * 68 + CW * ml] = f2bf(cv);
                const int jr = ml >> 1;
                const int q = (ml & 1) * 16 + (p >> 3);
                *reinterpret_cast<unsigned short*>(
                    h_out + jr * 512 + ((q ^ (jr & 7)) << 4) + (p & 7) * 2)
                    = f2bf(hv);
            }
        }
    }
}

// logits for M local nodes from swizzled LDS h; 4 lanes per node.
// Dots (no bias) go to the LDS stash; global store happens once at kernel end.
__device__ __forceinline__ void logits_stash(
    const unsigned char* h_lds, int M, int stBase,
    const float* __restrict__ W_lin, float* sL, int t)
{
    const int s = t >> 2, sub = t & 3;
    if (s >= M) return;
    float hv[32];
    const int j = s >> 1;
    #pragma unroll
    for (int qq = 0; qq < 4; ++qq) {
        const int q = (s & 1) * 16 + sub * 4 + qq;
        short8 v = *reinterpret_cast<const short8*>(
            h_lds + j * 512 + ((q ^ (j & 7)) << 4));
        #pragma unroll
        for (int e = 0; e < 8; ++e) hv[qq * 8 + e] = bf2f((unsigned short)v[e]);
    }
    float dots[5];
    #pragma unroll
    for (int cl = 0; cl < 5; ++cl) {
        const float* wr = W_lin + cl * 128 + sub * 32;
        float d = 0.f;
        #pragma unroll
        for (int k = 0; k < 32; ++k) d += hv[k] * wr[k];
        d += __shfl_xor(d, 1);
        d += __shfl_xor(d, 2);
        dots[cl] = d;
    }
    if (sub == 0) {
        #pragma unroll
        for (int cl = 0; cl < 5; ++cl)
            sL[(stBase + s) * 5 + cl] = dots[cl];
    }
}

// ---------------------------------------------------------------------------
__global__ __launch_bounds__(THREADS, 6)   // 6 waves/EU => 3 blocks/CU; VGPR<=85
void tree_kernel(const int*  __restrict__ leaf_x,
                 const int2* __restrict__ cpairs,   // l1:[0,131072) l2:+131072 l3:+196608
                 const float* __restrict__ emb,
                 const unsigned short* __restrict__ Wl,
                 const unsigned short* __restrict__ Wc,
                 const float* __restrict__ b_iou,
                 const float* __restrict__ b_f,
                 const float* __restrict__ W_lin,
                 const float* __restrict__ b_lin,
                 float* __restrict__ out)
{
    // Arena (52576 B), region-overlaid (lifetimes commented):
    //   X0  [0,16384)      leaf half B-tile (32 rows x 512B); dead after leaf
    //   h0  [16384,32768)  64 leaf slots (32 rows); dead after L1 GEMM
    //   cAr [32768,50176)  [p=128][68] ushort in-place c-arena, whole kernel
    //   sL  [50176,52576)  120x5 f32 logits stash, whole kernel
    //   h1  [0,8192)       over X0 after leaf barrier; dead after L2 GEMM
    //   h2  [16384,20480)  over h0 after L1 barrier (L3 GEMM also reads
    //                      stale rows 8..15 at [20480,24576); masked)
    //   h3  [0,2048)       over h1 after L2 barrier
    __shared__ __align__(16) unsigned char arena[52576];
    __shared__ int ids0[64], ids1[32], ids2[16], tok[64], sg[120];

    const int t    = threadIdx.x;
    const int lane = t & 63;
    const int w    = t >> 6;       // wave = p-slice, 8 waves
    const int lrow = lane & 15;
    const int lk   = lane >> 4;
    const int blk3 = blockIdx.x * 8;   // 8 level-3 roots per block

    // ---- id chase: local slot s's children are local slots 2s,2s+1 ----
    if (t < 8)  { int2 p = cpairs[196608 + blk3 + t]; ids2[2*t] = p.x; ids2[2*t+1] = p.y; }
    __syncthreads();
    if (t < 16) { int2 p = cpairs[131072 + ids2[t]];  ids1[2*t] = p.x; ids1[2*t+1] = p.y; }
    __syncthreads();
    if (t < 32) { int2 p = cpairs[ids1[t]];           ids0[2*t] = p.x; ids0[2*t+1] = p.y; }
    __syncthreads();
    if      (t < 64)  { tok[t] = leaf_x[ids0[t]]; sg[t] = ids0[t]; }
    else if (t < 96)  { sg[t] = 262144 + ids1[t - 64]; }
    else if (t < 112) { sg[t] = 393216 + ids2[t - 96]; }
    else if (t < 120) { sg[t] = 458752 + blk3 + (t - 112); }
    __syncthreads();

    unsigned char*  X0  = arena;
    unsigned char*  h0  = arena + 16384;
    unsigned short* cAr = (unsigned short*)(arena + 32768);
    float*          sL  = (float*)(arena + 50176);
    unsigned char*  h1  = arena;
    unsigned char*  h2  = arena + 16384;
    unsigned char*  h3  = arena;

    // ---- leaves: 64 nodes in two 32-row halves ----
    #pragma unroll 1
    for (int half = 0; half < 2; ++half) {
        {
            const int c  = t & 31;      // 16B chunk
            const int r0 = t >> 5;      // [0,16)
            #pragma unroll
            for (int rr = 0; rr < 2; ++rr) {
                const int r  = r0 + rr * 16;           // [0,32)
                const int gi = tok[half * 32 + r];
                const float4* src = reinterpret_cast<const float4*>(
                    emb + (size_t)gi * 256 + c * 8);
                float4 a = src[0], b = src[1];
                short8 v;
                v[0]=(short)f2bf(a.x); v[1]=(short)f2bf(a.y);
                v[2]=(short)f2bf(a.z); v[3]=(short)f2bf(a.w);
                v[4]=(short)f2bf(b.x); v[5]=(short)f2bf(b.y);
                v[6]=(short)f2bf(b.z); v[7]=(short)f2bf(b.w);
                *reinterpret_cast<short8*>(X0 + r * 512 + ((c ^ (r & 7)) << 4)) = v;
            }
        }
        __syncthreads();
        level_step<3, 2, 1, true>(Wl, X0, h0, cAr, b_iou, b_f,
                                  w, lrow, lk, half * 32, 32);
        __syncthreads();
    }

    // ---- level 1: 32 nodes ----
    logits_stash(h0, 64, 0, W_lin, sL, t);
    level_step<5, 2, 2, true>(Wc, h0, h1, cAr, b_iou, b_f,
                              w, lrow, lk, 0, 32);
    __syncthreads();

    // ---- level 2: 16 nodes ----
    logits_stash(h1, 32, 64, W_lin, sL, t);
    level_step<5, 1, 4, true>(Wc, h1, h2, cAr, b_iou, b_f,
                              w, lrow, lk, 0, 16);
    __syncthreads();

    // ---- level 3: 8 nodes (rows 8..15 of the 16-row m-group are stale; masked)
    logits_stash(h2, 16, 96, W_lin, sL, t);
    level_step<5, 1, 8, false>(Wc, h2, h3, cAr, b_iou, b_f,
                               w, lrow, lk, 0, 8);
    __syncthreads();

    logits_stash(h3, 8, 112, W_lin, sL, t);
    __syncthreads();

    // ---- single scattered-store burst; no barrier after (drains at kernel end)
    if (t < 120) {
        const float* sp = sL + t * 5;
        float* op = out + (size_t)sg[t] * 5;
        f32x4 v4 = { sp[0] + b_lin[0], sp[1] + b_lin[1],
                     sp[2] + b_lin[2], sp[3] + b_lin[3] };
        *reinterpret_cast<f32x4u*>(op) = v4;
        op[4] = sp[4] + b_lin[4];
    }
}

// ---------------------------------------------------------------------------
extern "C" void kernel_launch(void* const* d_in, const int* in_sizes, int n_in,
                              void* d_out, int out_size, void* d_ws, size_t ws_size,
                              hipStream_t stream)
{
    const int*   leaf_x = (const int*)d_in[0];
    const int*   child  = (const int*)d_in[1];
    const float* emb    = (const float*)d_in[2];
    const float* W_iou  = (const float*)d_in[3];
    const float* U_iou  = (const float*)d_in[4];
    const float* b_iou  = (const float*)d_in[5];
    const float* U_f    = (const float*)d_in[6];
    const float* b_f    = (const float*)d_in[7];
    const float* W_lin  = (const float*)d_in[8];
    const float* b_lin  = (const float*)d_in[9];
    float* out = (float*)d_out;

    char* ws = (char*)d_ws;
    unsigned short* Wl = (unsigned short*)ws;                 // 192 KiB
    unsigned short* Wc = (unsigned short*)(ws + 196608);      // 320 KiB

    prep_kernel<<<384, 256, 0, stream>>>(W_iou, U_iou, U_f, Wl, Wc);

    tree_kernel<<<4096, THREADS, 0, stream>>>(
        leaf_x, (const int2*)child, emb, Wl, Wc,
        b_iou, b_f, W_lin, b_lin, out);
}

// Round 9
// 979.779 us; speedup vs baseline: 1.2349x; 1.2055x over previous
//
#include <hip/hip_runtime.h>
#include <hip/hip_bf16.h>
#include <stdint.h>

// TreeLSTM on MI355X (gfx950) — fully fused subtree kernel, v6.
// Each block owns 8 level-3 roots => 64 leaves. All h/c state lives in LDS.
// v6 = v5 with launch_bounds(512,4): the (512,6) cap (~85 VGPR) forced the
// allocator to spill accumulators to scratch (VGPR=40, 3.2GB scratch traffic,
// rounds 7+8). At (512,4) the same body compiles to VGPR=64 naturally (rounds
// 4/6) — and since hardware residency follows ACTUAL vgpr/LDS, 64 VGPR +
// 53760B LDS still admits 3 blocks/CU (24 waves) without spilling.
// Keeps: LDS logits stash with ONE scattered-store burst at kernel end;
// in-place [p][68] c-arena; exp/rcp tanh/sigmoid; idempotent weight packing.

#define THREADS 512

typedef __attribute__((ext_vector_type(8))) short short8;
typedef __attribute__((ext_vector_type(4))) float f32x4;
typedef f32x4 __attribute__((aligned(4))) f32x4u;   // 4B-aligned vec store

__device__ __forceinline__ unsigned short f2bf(float x) {
    unsigned u = __float_as_uint(x);
    u += 0x7fffu + ((u >> 16) & 1u);   // round-to-nearest-even
    return (unsigned short)(u >> 16);
}
__device__ __forceinline__ float bf2f(unsigned short b) {
    return __uint_as_float(((unsigned)b) << 16);
}
__device__ __forceinline__ float rcp_fast(float x) { return __builtin_amdgcn_rcpf(x); }
__device__ __forceinline__ float sigm(float x) { return rcp_fast(1.f + __expf(-x)); }
__device__ __forceinline__ float tanh_fast(float x) {
    float e = __expf(2.f * x);
    return (e - 1.f) * rcp_fast(e + 1.f);
}

// ---------------------------------------------------------------------------
// Pack W_iou (384x256) -> Wl ; [U_iou (384x256); U_f (256x256)] -> Wc (640x256)
__global__ __launch_bounds__(256)
void prep_kernel(const float* __restrict__ W_iou,
                 const float* __restrict__ U_iou,
                 const float* __restrict__ U_f,
                 unsigned short* __restrict__ Wl,
                 unsigned short* __restrict__ Wc)
{
    const int i = blockIdx.x * 256 + threadIdx.x;   // grid covers 98304
    if (i < 98304) {
        Wl[i] = f2bf(W_iou[i]);
        Wc[i] = f2bf(U_iou[i]);
    }
    if (i < 65536) {
        Wc[98304 + i] = f2bf(U_f[i]);
    }
}

// ---------------------------------------------------------------------------
// One level's GEMM + LSTM epilogue.
// B-tile rows (512B, XOR-16B-chunk swizzled): row j = [h_prev[2j]|h_prev[2j+1]]
// (leaves: row i = emb[tok[i]]). Swapped MFMA: D[n][node]; wave w owns the
// p-slice [16w,16w+16); col groups n = p + j*128 keep i,o,u,f0,f1 in one lane.
// c-arena: one [p][68]-padded ushort buffer; level-l slot s at index s<<l.
// CW = 1<<level. Children of node ml sit at CW*ml and CW*ml + CW/2; own c is
// written at CW*ml (aliases first child; same thread reads both first).
template<int NCOL, int G, int CW, bool WC>
__device__ __forceinline__ void level_step(
    const unsigned short* __restrict__ Wg,     // [NCOL*128][256] bf16, global
    const unsigned char* Blds,                 // B-tile base in LDS
    unsigned char* h_out,                      // LDS, B-tile format for next level
    unsigned short* cAr,                       // LDS c-arena, stride 68 per p
    const float* __restrict__ b_iou, const float* __restrict__ b_f,
    int w, int lrow, int lk, int slotBase, int mrows)
{
    const int q0 = w * 16;
    const unsigned char* wbase = reinterpret_cast<const unsigned char*>(Wg)
                               + (q0 + lrow) * 512 + lk * 16;

    f32x4 acc[NCOL][G];
    #pragma unroll
    for (int j = 0; j < NCOL; ++j)
        #pragma unroll
        for (int g = 0; g < G; ++g)
            acc[j][g] = (f32x4){0.f, 0.f, 0.f, 0.f};

    #pragma unroll
    for (int ks = 0; ks < 8; ++ks) {
        short8 aW[NCOL];
        #pragma unroll
        for (int j = 0; j < NCOL; ++j)
            aW[j] = *reinterpret_cast<const short8*>(
                wbase + j * 65536 + ks * 64);
        #pragma unroll
        for (int g = 0; g < G; ++g) {
            const int row = g * 16 + lrow;          // B-tile row
            const int chunk = (ks * 4 + lk) ^ (row & 7);
            short8 bN = *reinterpret_cast<const short8*>(
                Blds + row * 512 + (chunk << 4));
            #pragma unroll
            for (int j = 0; j < NCOL; ++j)
                acc[j][g] = __builtin_amdgcn_mfma_f32_16x16x32_bf16(
                    aW[j], bN, acc[j][g], 0, 0, 0);
        }
    }

    #pragma unroll
    for (int g = 0; g < G; ++g) {
        const int mlB = g * 16 + lrow;              // B-tile row index
        if (mlB < mrows) {
            const int ml = slotBase + mlB;          // output slot this level
            #pragma unroll
            for (int r = 0; r < 4; ++r) {
                const int p = q0 + lk * 4 + r;
                float iv = acc[0][g][r] + b_iou[p];
                float ov = acc[1][g][r] + b_iou[128 + p];
                float uv = acc[2][g][r] + b_iou[256 + p];
                float csum = 0.f;
                if (NCOL == 5) {
                    float f0 = acc[3][g][r] + b_f[p];
                    float f1 = acc[4][g][r] + b_f[128 + p];
                    const int cb = p * 68 + CW * mlB;
                    csum = sigm(f0) * bf2f(cAr[cb])
                         + sigm(f1) * bf2f(cAr[cb + CW / 2]);
                }
                float cv = sigm(iv) * tanh_fast(uv) + csum;
                float hv = sigm(ov) * tanh_fast(cv);
                if (WC) cAr[p * 68 + CW * ml] = f2bf(cv);
                const int jr = ml >> 1;
                const int q = (ml & 1) * 16 + (p >> 3);
                *reinterpret_cast<unsigned short*>(
                    h_out + jr * 512 + ((q ^ (jr & 7)) << 4) + (p & 7) * 2)
                    = f2bf(hv);
            }
        }
    }
}

// logits for M local nodes from swizzled LDS h; 4 lanes per node.
// Dots (no bias) go to the LDS stash; global store happens once at kernel end.
__device__ __forceinline__ void logits_stash(
    const unsigned char* h_lds, int M, int stBase,
    const float* __restrict__ W_lin, float* sL, int t)
{
    const int s = t >> 2, sub = t & 3;
    if (s >= M) return;
    float hv[32];
    const int j = s >> 1;
    #pragma unroll
    for (int qq = 0; qq < 4; ++qq) {
        const int q = (s & 1) * 16 + sub * 4 + qq;
        short8 v = *reinterpret_cast<const short8*>(
            h_lds + j * 512 + ((q ^ (j & 7)) << 4));
        #pragma unroll
        for (int e = 0; e < 8; ++e) hv[qq * 8 + e] = bf2f((unsigned short)v[e]);
    }
    float dots[5];
    #pragma unroll
    for (int cl = 0; cl < 5; ++cl) {
        const float* wr = W_lin + cl * 128 + sub * 32;
        float d = 0.f;
        #pragma unroll
        for (int k = 0; k < 32; ++k) d += hv[k] * wr[k];
        d += __shfl_xor(d, 1);
        d += __shfl_xor(d, 2);
        dots[cl] = d;
    }
    if (sub == 0) {
        #pragma unroll
        for (int cl = 0; cl < 5; ++cl)
            sL[(stBase + s) * 5 + cl] = dots[cl];
    }
}

// ---------------------------------------------------------------------------
__global__ __launch_bounds__(THREADS, 4)   // VGPR cap 128; body compiles to ~64
void tree_kernel(const int*  __restrict__ leaf_x,
                 const int2* __restrict__ cpairs,   // l1:[0,131072) l2:+131072 l3:+196608
                 const float* __restrict__ emb,
                 const unsigned short* __restrict__ Wl,
                 const unsigned short* __restrict__ Wc,
                 const float* __restrict__ b_iou,
                 const float* __restrict__ b_f,
                 const float* __restrict__ W_lin,
                 const float* __restrict__ b_lin,
                 float* __restrict__ out)
{
    // Arena (52576 B), region-overlaid (lifetimes commented):
    //   X0  [0,16384)      leaf half B-tile (32 rows x 512B); dead after leaf
    //   h0  [16384,32768)  64 leaf slots (32 rows); dead after L1 GEMM
    //   cAr [32768,50176)  [p=128][68] ushort in-place c-arena, whole kernel
    //   sL  [50176,52576)  120x5 f32 logits stash, whole kernel
    //   h1  [0,8192)       over X0 after leaf barrier; dead after L2 GEMM
    //   h2  [16384,20480)  over h0 after L1 barrier (L3 GEMM also reads
    //                      stale rows 8..15 at [20480,24576); masked)
    //   h3  [0,2048)       over h1 after L2 barrier
    __shared__ __align__(16) unsigned char arena[52576];
    __shared__ int ids0[64], ids1[32], ids2[16], tok[64], sg[120];

    const int t    = threadIdx.x;
    const int lane = t & 63;
    const int w    = t >> 6;       // wave = p-slice, 8 waves
    const int lrow = lane & 15;
    const int lk   = lane >> 4;
    const int blk3 = blockIdx.x * 8;   // 8 level-3 roots per block

    // ---- id chase: local slot s's children are local slots 2s,2s+1 ----
    if (t < 8)  { int2 p = cpairs[196608 + blk3 + t]; ids2[2*t] = p.x; ids2[2*t+1] = p.y; }
    __syncthreads();
    if (t < 16) { int2 p = cpairs[131072 + ids2[t]];  ids1[2*t] = p.x; ids1[2*t+1] = p.y; }
    __syncthreads();
    if (t < 32) { int2 p = cpairs[ids1[t]];           ids0[2*t] = p.x; ids0[2*t+1] = p.y; }
    __syncthreads();
    if      (t < 64)  { tok[t] = leaf_x[ids0[t]]; sg[t] = ids0[t]; }
    else if (t < 96)  { sg[t] = 262144 + ids1[t - 64]; }
    else if (t < 112) { sg[t] = 393216 + ids2[t - 96]; }
    else if (t < 120) { sg[t] = 458752 + blk3 + (t - 112); }
    __syncthreads();

    unsigned char*  X0  = arena;
    unsigned char*  h0  = arena + 16384;
    unsigned short* cAr = (unsigned short*)(arena + 32768);
    float*          sL  = (float*)(arena + 50176);
    unsigned char*  h1  = arena;
    unsigned char*  h2  = arena + 16384;
    unsigned char*  h3  = arena;

    // ---- leaves: 64 nodes in two 32-row halves ----
    #pragma unroll 1
    for (int half = 0; half < 2; ++half) {
        {
            const int c  = t & 31;      // 16B chunk
            const int r0 = t >> 5;      // [0,16)
            #pragma unroll
            for (int rr = 0; rr < 2; ++rr) {
                const int r  = r0 + rr * 16;           // [0,32)
                const int gi = tok[half * 32 + r];
                const float4* src = reinterpret_cast<const float4*>(
                    emb + (size_t)gi * 256 + c * 8);
                float4 a = src[0], b = src[1];
                short8 v;
                v[0]=(short)f2bf(a.x); v[1]=(short)f2bf(a.y);
                v[2]=(short)f2bf(a.z); v[3]=(short)f2bf(a.w);
                v[4]=(short)f2bf(b.x); v[5]=(short)f2bf(b.y);
                v[6]=(short)f2bf(b.z); v[7]=(short)f2bf(b.w);
                *reinterpret_cast<short8*>(X0 + r * 512 + ((c ^ (r & 7)) << 4)) = v;
            }
        }
        __syncthreads();
        level_step<3, 2, 1, true>(Wl, X0, h0, cAr, b_iou, b_f,
                                  w, lrow, lk, half * 32, 32);
        __syncthreads();
    }

    // ---- level 1: 32 nodes ----
    logits_stash(h0, 64, 0, W_lin, sL, t);
    level_step<5, 2, 2, true>(Wc, h0, h1, cAr, b_iou, b_f,
                              w, lrow, lk, 0, 32);
    __syncthreads();

    // ---- level 2: 16 nodes ----
    logits_stash(h1, 32, 64, W_lin, sL, t);
    level_step<5, 1, 4, true>(Wc, h1, h2, cAr, b_iou, b_f,
                              w, lrow, lk, 0, 16);
    __syncthreads();

    // ---- level 3: 8 nodes (rows 8..15 of the 16-row m-group are stale; masked)
    logits_stash(h2, 16, 96, W_lin, sL, t);
    level_step<5, 1, 8, false>(Wc, h2, h3, cAr, b_iou, b_f,
                               w, lrow, lk, 0, 8);
    __syncthreads();

    logits_stash(h3, 8, 112, W_lin, sL, t);
    __syncthreads();

    // ---- single scattered-store burst; no barrier after (drains at kernel end)
    if (t < 120) {
        const float* sp = sL + t * 5;
        float* op = out + (size_t)sg[t] * 5;
        f32x4 v4 = { sp[0] + b_lin[0], sp[1] + b_lin[1],
                     sp[2] + b_lin[2], sp[3] + b_lin[3] };
        *reinterpret_cast<f32x4u*>(op) = v4;
        op[4] = sp[4] + b_lin[4];
    }
}

// ---------------------------------------------------------------------------
extern "C" void kernel_launch(void* const* d_in, const int* in_sizes, int n_in,
                              void* d_out, int out_size, void* d_ws, size_t ws_size,
                              hipStream_t stream)
{
    const int*   leaf_x = (const int*)d_in[0];
    const int*   child  = (const int*)d_in[1];
    const float* emb    = (const float*)d_in[2];
    const float* W_iou  = (const float*)d_in[3];
    const float* U_iou  = (const float*)d_in[4];
    const float* b_iou  = (const float*)d_in[5];
    const float* U_f    = (const float*)d_in[6];
    const float* b_f    = (const float*)d_in[7];
    const float* W_lin  = (const float*)d_in[8];
    const float* b_lin  = (const float*)d_in[9];
    float* out = (float*)d_out;

    char* ws = (char*)d_ws;
    unsigned short* Wl = (unsigned short*)ws;                 // 192 KiB
    unsigned short* Wc = (unsigned short*)(ws + 196608);      // 320 KiB

    prep_kernel<<<384, 256, 0, stream>>>(W_iou, U_iou, U_f, Wl, Wc);

    tree_kernel<<<4096, THREADS, 0, stream>>>(
        leaf_x, (const int2*)child, emb, Wl, Wc,
        b_iou, b_f, W_lin, b_lin, out);
}

// Round 10
// 903.395 us; speedup vs baseline: 1.3393x; 1.0846x over previous
//
#include <hip/hip_runtime.h>
#include <hip/hip_bf16.h>
#include <stdint.h>

// TreeLSTM on MI355X (gfx950) — fully fused subtree kernel, v7.
// Each block owns 8 level-3 roots => 64 leaves. All h/c state lives in LDS.
// v7: occupancy fix. r9 showed 53,760B LDS -> still 2 blocks/CU, consistent
// with 2KiB LDS allocation granularity (3x round2K(53760)=55296 > 163840).
// Shaves: c-arena pad 68->66 (-512B), drop the logits stash/burst (-2880B;
// the burst also MEASURABLY amplified writes 518MB->1.28GB, so revert to
// per-level scalar-dword emits = r4's best-measured pattern). New block LDS
// = 50,368B -> round2K 51,200 -> 3 blocks/CU (24 waves, +50% latency hiding).
// Keeps: in-place c-arena, exp/rcp activations, (512,4) bounds (VGPR 64).

#define THREADS 512

typedef __attribute__((ext_vector_type(8))) short short8;
typedef __attribute__((ext_vector_type(4))) float f32x4;

__device__ __forceinline__ unsigned short f2bf(float x) {
    unsigned u = __float_as_uint(x);
    u += 0x7fffu + ((u >> 16) & 1u);   // round-to-nearest-even
    return (unsigned short)(u >> 16);
}
__device__ __forceinline__ float bf2f(unsigned short b) {
    return __uint_as_float(((unsigned)b) << 16);
}
__device__ __forceinline__ float rcp_fast(float x) { return __builtin_amdgcn_rcpf(x); }
__device__ __forceinline__ float sigm(float x) { return rcp_fast(1.f + __expf(-x)); }
__device__ __forceinline__ float tanh_fast(float x) {
    float e = __expf(2.f * x);
    return (e - 1.f) * rcp_fast(e + 1.f);
}

// ---------------------------------------------------------------------------
// Pack W_iou (384x256) -> Wl ; [U_iou (384x256); U_f (256x256)] -> Wc (640x256)
__global__ __launch_bounds__(256)
void prep_kernel(const float* __restrict__ W_iou,
                 const float* __restrict__ U_iou,
                 const float* __restrict__ U_f,
                 unsigned short* __restrict__ Wl,
                 unsigned short* __restrict__ Wc)
{
    const int i = blockIdx.x * 256 + threadIdx.x;   // grid covers 98304
    if (i < 98304) {
        Wl[i] = f2bf(W_iou[i]);
        Wc[i] = f2bf(U_iou[i]);
    }
    if (i < 65536) {
        Wc[98304 + i] = f2bf(U_f[i]);
    }
}

// ---------------------------------------------------------------------------
// One level's GEMM + LSTM epilogue.
// B-tile rows (512B, XOR-16B-chunk swizzled): row j = [h_prev[2j]|h_prev[2j+1]]
// (leaves: row i = emb[tok[i]]). Swapped MFMA: D[n][node]; wave w owns the
// p-slice [16w,16w+16); col groups n = p + j*128 keep i,o,u,f0,f1 in one lane.
// c-arena: one [p][66]-padded ushort buffer; level-l slot s at index s<<l.
// CW = 1<<level. Children of node ml sit at CW*ml and CW*ml + CW/2; own c is
// written at CW*ml (aliases first child; same thread reads both first).
template<int NCOL, int G, int CW, bool WC>
__device__ __forceinline__ void level_step(
    const unsigned short* __restrict__ Wg,     // [NCOL*128][256] bf16, global
    const unsigned char* Blds,                 // B-tile base in LDS
    unsigned char* h_out,                      // LDS, B-tile format for next level
    unsigned short* cAr,                       // LDS c-arena, stride 66 per p
    const float* __restrict__ b_iou, const float* __restrict__ b_f,
    int w, int lrow, int lk, int slotBase, int mrows)
{
    const int q0 = w * 16;
    const unsigned char* wbase = reinterpret_cast<const unsigned char*>(Wg)
                               + (q0 + lrow) * 512 + lk * 16;

    f32x4 acc[NCOL][G];
    #pragma unroll
    for (int j = 0; j < NCOL; ++j)
        #pragma unroll
        for (int g = 0; g < G; ++g)
            acc[j][g] = (f32x4){0.f, 0.f, 0.f, 0.f};

    #pragma unroll
    for (int ks = 0; ks < 8; ++ks) {
        short8 aW[NCOL];
        #pragma unroll
        for (int j = 0; j < NCOL; ++j)
            aW[j] = *reinterpret_cast<const short8*>(
                wbase + j * 65536 + ks * 64);
        #pragma unroll
        for (int g = 0; g < G; ++g) {
            const int row = g * 16 + lrow;          // B-tile row
            const int chunk = (ks * 4 + lk) ^ (row & 7);
            short8 bN = *reinterpret_cast<const short8*>(
                Blds + row * 512 + (chunk << 4));
            #pragma unroll
            for (int j = 0; j < NCOL; ++j)
                acc[j][g] = __builtin_amdgcn_mfma_f32_16x16x32_bf16(
                    aW[j], bN, acc[j][g], 0, 0, 0);
        }
    }

    #pragma unroll
    for (int g = 0; g < G; ++g) {
        const int mlB = g * 16 + lrow;              // B-tile row index
        if (mlB < mrows) {
            const int ml = slotBase + mlB;          // output slot this level
            #pragma unroll
            for (int r = 0; r < 4; ++r) {
                const int p = q0 + lk * 4 + r;
                float iv = acc[0][g][r] + b_iou[p];
                float ov = acc[1][g][r] + b_iou[128 + p];
                float uv = acc[2][g][r] + b_iou[256 + p];
                float csum = 0.f;
                if (NCOL == 5) {
                    float f0 = acc[3][g][r] + b_f[p];
                    float f1 = acc[4][g][r] + b_f[128 + p];
                    const int cb = p * 66 + CW * mlB;
                    csum = sigm(f0) * bf2f(cAr[cb])
                         + sigm(f1) * bf2f(cAr[cb + CW / 2]);
                }
                float cv = sigm(iv) * tanh_fast(uv) + csum;
                float hv = sigm(ov) * tanh_fast(cv);
                if (WC) cAr[p * 66 + CW * ml] = f2bf(cv);
                const int jr = ml >> 1;
                const int q = (ml & 1) * 16 + (p >> 3);
                *reinterpret_cast<unsigned short*>(
                    h_out + jr * 512 + ((q ^ (jr & 7)) << 4) + (p & 7) * 2)
                    = f2bf(hv);
            }
        }
    }
}

// logits for M local nodes from swizzled LDS h; 4 lanes per node.
// Per-level emit, 5 scalar dword stores from sub==0 (r4's best-measured form).
__device__ __forceinline__ void logits_emit(
    const unsigned char* h_lds, int M, const int* idsLds, int idBase,
    int segOff, const float* __restrict__ W_lin, const float* __restrict__ b_lin,
    float* __restrict__ out, int t)
{
    const int s = t >> 2, sub = t & 3;
    if (s >= M) return;
    float hv[32];
    const int j = s >> 1;
    #pragma unroll
    for (int qq = 0; qq < 4; ++qq) {
        const int q = (s & 1) * 16 + sub * 4 + qq;
        short8 v = *reinterpret_cast<const short8*>(
            h_lds + j * 512 + ((q ^ (j & 7)) << 4));
        #pragma unroll
        for (int e = 0; e < 8; ++e) hv[qq * 8 + e] = bf2f((unsigned short)v[e]);
    }
    const int gid = idsLds ? idsLds[s] : (idBase + s);
    float dots[5];
    #pragma unroll
    for (int cl = 0; cl < 5; ++cl) {
        const float* wr = W_lin + cl * 128 + sub * 32;
        float d = 0.f;
        #pragma unroll
        for (int k = 0; k < 32; ++k) d += hv[k] * wr[k];
        d += __shfl_xor(d, 1);
        d += __shfl_xor(d, 2);
        dots[cl] = d;
    }
    if (sub == 0) {
        float* op = out + (size_t)(segOff + gid) * 5;
        #pragma unroll
        for (int cl = 0; cl < 5; ++cl)
            op[cl] = dots[cl] + b_lin[cl];
    }
}

// ---------------------------------------------------------------------------
__global__ __launch_bounds__(THREADS, 4)   // VGPR cap 128; body compiles to ~64
void tree_kernel(const int*  __restrict__ leaf_x,
                 const int2* __restrict__ cpairs,   // l1:[0,131072) l2:+131072 l3:+196608
                 const float* __restrict__ emb,
                 const unsigned short* __restrict__ Wl,
                 const unsigned short* __restrict__ Wc,
                 const float* __restrict__ b_iou,
                 const float* __restrict__ b_f,
                 const float* __restrict__ W_lin,
                 const float* __restrict__ b_lin,
                 float* __restrict__ out)
{
    // Arena (49664 B), region-overlaid (lifetimes commented):
    //   A [0,16384):       X0 leaf half B-tile (32 rows x 512B); dead after leaf
    //                      -> h1 [0,8192) (dead after L2 GEMM); h3 [8192,10240)
    //   B [16384,32768):   h0 (32 rows); dead after L1 GEMM
    //                      -> h2 [16384,24576) (real rows 0..7; rows 8..15 hold
    //                         stale-but-finite h0 data, outputs masked)
    //   C [32768,49664):   cAr [p=128][66] ushort in-place c-arena, whole kernel
    // Total block LDS = 49664 + 704 (ids) = 50368 -> 3 blocks/CU at 2KiB gran.
    __shared__ __align__(16) unsigned char arena[49664];
    __shared__ int ids0[64], ids1[32], ids2[16], tok[64];

    const int t    = threadIdx.x;
    const int lane = t & 63;
    const int w    = t >> 6;       // wave = p-slice, 8 waves
    const int lrow = lane & 15;
    const int lk   = lane >> 4;
    const int blk3 = blockIdx.x * 8;   // 8 level-3 roots per block

    // ---- id chase: local slot s's children are local slots 2s,2s+1 ----
    if (t < 8)  { int2 p = cpairs[196608 + blk3 + t]; ids2[2*t] = p.x; ids2[2*t+1] = p.y; }
    __syncthreads();
    if (t < 16) { int2 p = cpairs[131072 + ids2[t]];  ids1[2*t] = p.x; ids1[2*t+1] = p.y; }
    __syncthreads();
    if (t < 32) { int2 p = cpairs[ids1[t]];           ids0[2*t] = p.x; ids0[2*t+1] = p.y; }
    __syncthreads();
    if (t < 64) { tok[t] = leaf_x[ids0[t]]; }
    __syncthreads();

    unsigned char*  X0  = arena;
    unsigned char*  h0  = arena + 16384;
    unsigned short* cAr = (unsigned short*)(arena + 32768);
    unsigned char*  h1  = arena;
    unsigned char*  h2  = arena + 16384;
    unsigned char*  h3  = arena + 8192;

    // ---- leaves: 64 nodes in two 32-row halves ----
    #pragma unroll 1
    for (int half = 0; half < 2; ++half) {
        {
            const int c  = t & 31;      // 16B chunk
            const int r0 = t >> 5;      // [0,16)
            #pragma unroll
            for (int rr = 0; rr < 2; ++rr) {
                const int r  = r0 + rr * 16;           // [0,32)
                const int gi = tok[half * 32 + r];
                const float4* src = reinterpret_cast<const float4*>(
                    emb + (size_t)gi * 256 + c * 8);
                float4 a = src[0], b = src[1];
                short8 v;
                v[0]=(short)f2bf(a.x); v[1]=(short)f2bf(a.y);
                v[2]=(short)f2bf(a.z); v[3]=(short)f2bf(a.w);
                v[4]=(short)f2bf(b.x); v[5]=(short)f2bf(b.y);
                v[6]=(short)f2bf(b.z); v[7]=(short)f2bf(b.w);
                *reinterpret_cast<short8*>(X0 + r * 512 + ((c ^ (r & 7)) << 4)) = v;
            }
        }
        __syncthreads();
        level_step<3, 2, 1, true>(Wl, X0, h0, cAr, b_iou, b_f,
                                  w, lrow, lk, half * 32, 32);
        __syncthreads();
    }

    // ---- level 1: 32 nodes ----
    logits_emit(h0, 64, ids0, 0, 0, W_lin, b_lin, out, t);
    level_step<5, 2, 2, true>(Wc, h0, h1, cAr, b_iou, b_f,
                              w, lrow, lk, 0, 32);
    __syncthreads();

    // ---- level 2: 16 nodes ----
    logits_emit(h1, 32, ids1, 0, 262144, W_lin, b_lin, out, t);
    level_step<5, 1, 4, true>(Wc, h1, h2, cAr, b_iou, b_f,
                              w, lrow, lk, 0, 16);
    __syncthreads();

    // ---- level 3: 8 nodes (rows 8..15 of the 16-row m-group are stale; masked)
    logits_emit(h2, 16, ids2, 0, 393216, W_lin, b_lin, out, t);
    level_step<5, 1, 8, false>(Wc, h2, h3, cAr, b_iou, b_f,
                               w, lrow, lk, 0, 8);
    __syncthreads();

    logits_emit(h3, 8, nullptr, blk3, 458752, W_lin, b_lin, out, t);
}

// ---------------------------------------------------------------------------
extern "C" void kernel_launch(void* const* d_in, const int* in_sizes, int n_in,
                              void* d_out, int out_size, void* d_ws, size_t ws_size,
                              hipStream_t stream)
{
    const int*   leaf_x = (const int*)d_in[0];
    const int*   child  = (const int*)d_in[1];
    const float* emb    = (const float*)d_in[2];
    const float* W_iou  = (const float*)d_in[3];
    const float* U_iou  = (const float*)d_in[4];
    const float* b_iou  = (const float*)d_in[5];
    const float* U_f    = (const float*)d_in[6];
    const float* b_f    = (const float*)d_in[7];
    const float* W_lin  = (const float*)d_in[8];
    const float* b_lin  = (const float*)d_in[9];
    float* out = (float*)d_out;

    char* ws = (char*)d_ws;
    unsigned short* Wl = (unsigned short*)ws;                 // 192 KiB
    unsigned short* Wc = (unsigned short*)(ws + 196608);      // 320 KiB

    prep_kernel<<<384, 256, 0, stream>>>(W_iou, U_iou, U_f, Wl, Wc);

    tree_kernel<<<4096, THREADS, 0, stream>>>(
        leaf_x, (const int2*)child, emb, Wl, Wc,
        b_iou, b_f, W_lin, b_lin, out);
}